// Round 11
// baseline (177.725 us; speedup 1.0000x reference)
//
#include <hip/hip_runtime.h>

typedef __bf16 bf16;
typedef __bf16 bf16_4 __attribute__((ext_vector_type(4)));
typedef __bf16 bf16_8 __attribute__((ext_vector_type(8)));
typedef float f32_4 __attribute__((ext_vector_type(4)));
typedef float f32_16 __attribute__((ext_vector_type(16)));

// async global->LDS, 16B per lane; LDS dest must be wave-uniform base + lane*16
#define GLDS16(g, l) \
  __builtin_amdgcn_global_load_lds((const __attribute__((address_space(1))) unsigned int*)(g), \
                                   (__attribute__((address_space(3))) unsigned int*)(l), 16, 0, 0)

// ---------------- fused f32 -> bf16 convert (grid-stride) ----------------
__global__ __launch_bounds__(256) void convert_all(
    const float* __restrict__ x, const float* __restrict__ wq, const float* __restrict__ wk,
    const float* __restrict__ wv, const float* __restrict__ wo,
    bf16* __restrict__ xb, bf16* __restrict__ wqb, bf16* __restrict__ wkb,
    bf16* __restrict__ wvb, bf16* __restrict__ wob)
{
    for (int i = blockIdx.x * 256 + threadIdx.x; i < 2097152; i += 2048 * 256) {
        const float* s; bf16* d; int off;
        if (i < 1048576) { s = x; d = xb; off = i; }
        else {
            int j = i - 1048576;
            int sel = j >> 18;
            off = j & 262143;
            s = (sel == 0) ? wq : (sel == 1) ? wk : (sel == 2) ? wv : wo;
            d = (sel == 0) ? wqb : (sel == 1) ? wkb : (sel == 2) ? wvb : wob;
        }
        float4 v = reinterpret_cast<const float4*>(s)[off];
        bf16_4 o; o.x = (bf16)v.x; o.y = (bf16)v.y; o.z = (bf16)v.z; o.w = (bf16)v.w;
        reinterpret_cast<bf16_4*>(d)[off] = o;
    }
}

// ---- 16x16x32 GEMM core (used by scores only): BM=128, KU=1 ----
template<int BM, int KU>
__device__ __forceinline__ void gemm_core(
    const bf16* __restrict__ Ab, int lda,
    const bf16* __restrict__ Wb, int ldw,
    int K, int m0, int n0, int tid,
    bf16* As, bf16* Bs,
    f32_4 (&acc)[4][(BM == 128) ? 4 : 2])
{
    constexpr int NJ = (BM == 128) ? 4 : 2;
    constexpr int CA = BM * 8;
    const int lane = tid & 63;
    const int wave = tid >> 6;
    const int l15  = lane & 15;
    const int quad = lane >> 4;
    const int WM = (BM == 128) ? (wave >> 1) * 64 : 0;
    const int WN = (BM == 128) ? (wave & 1) * 64 : wave * 32;

#pragma unroll
    for (int i = 0; i < 4; i++)
#pragma unroll
        for (int j = 0; j < NJ; j++) acc[i][j] = (f32_4)(0.0f);

    for (int k0 = 0; k0 < K; k0 += 64 * KU) {
#pragma unroll
        for (int ku = 0; ku < KU; ++ku) {
            bf16* Asu = As + ku * BM * 64;
            bf16* Bsu = Bs + ku * 128 * 64;
            int kk = k0 + ku * 64;
#pragma unroll
            for (int it = 0; it < CA / 256; ++it) {
                int p = wave * (CA / 4) + it * 64 + lane;
                int r = p >> 3;
                int q = (p & 7) ^ (r & 7);
                GLDS16(Ab + (long long)(m0 + r) * lda + kk + q * 8, Asu + p * 8);
            }
#pragma unroll
            for (int it = 0; it < 4; ++it) {
                int p = wave * 256 + it * 64 + lane;
                int r = p >> 3;
                int q = (p & 7) ^ (r & 7);
                GLDS16(Wb + (long long)(n0 + r) * ldw + kk + q * 8, Bsu + p * 8);
            }
        }
        __syncthreads();

#pragma unroll
        for (int ku = 0; ku < KU; ++ku) {
            bf16* Asu = As + ku * BM * 64;
            bf16* Bsu = Bs + ku * 128 * 64;
#pragma unroll
            for (int kh = 0; kh < 2; ++kh) {
                bf16_8 af[4], bfr[NJ];
#pragma unroll
                for (int t = 0; t < 4; ++t) {
                    int r = WM + t * 16 + l15;
                    int q = (kh * 4 + quad) ^ (r & 7);
                    af[t] = *reinterpret_cast<const bf16_8*>(&Asu[r * 64 + q * 8]);
                }
#pragma unroll
                for (int j = 0; j < NJ; ++j) {
                    int r = WN + j * 16 + l15;
                    int q = (kh * 4 + quad) ^ (r & 7);
                    bfr[j] = *reinterpret_cast<const bf16_8*>(&Bsu[r * 64 + q * 8]);
                }
#pragma unroll
                for (int i = 0; i < 4; ++i)
#pragma unroll
                    for (int j = 0; j < NJ; ++j)
                        acc[i][j] = __builtin_amdgcn_mfma_f32_16x16x32_bf16(af[i], bfr[j], acc[i][j], 0, 0, 0);
            }
        }
        __syncthreads();
    }
}

// ---- 32x32x16 GEMM core for BM=64 kernels: wave = 64x32 (2 stacked 32x32 m-tiles) ----
// A/B frag: 8 contiguous k per lane: row = (lane&31)(+t*32 / +WN), k = kstep*16 + 8*(lane>>5)+i
// C/D (m74-verified): col = lane&31, row = (reg&3) + 8*(reg>>2) + 4*(lane>>5)
template<int KU>
__device__ __forceinline__ void gemm_core32(
    const bf16* __restrict__ Ab, int lda,
    const bf16* __restrict__ Wb, int ldw,
    int K, int m0, int n0, int tid,
    bf16* As, bf16* Bs,
    f32_16 (&acc)[2])
{
    const int lane  = tid & 63;
    const int wave  = tid >> 6;
    const int l31   = lane & 31;
    const int khalf = lane >> 5;
    const int WN    = wave * 32;

    acc[0] = (f32_16)(0.0f);
    acc[1] = (f32_16)(0.0f);

    for (int k0 = 0; k0 < K; k0 += 64 * KU) {
#pragma unroll
        for (int ku = 0; ku < KU; ++ku) {
            bf16* Asu = As + ku * 4096;
            bf16* Bsu = Bs + ku * 8192;
            int kk = k0 + ku * 64;
#pragma unroll
            for (int it = 0; it < 2; ++it) {
                int p = wave * 128 + it * 64 + lane;
                int r = p >> 3, q = (p & 7) ^ (r & 7);
                GLDS16(Ab + (long long)(m0 + r) * lda + kk + q * 8, Asu + p * 8);
            }
#pragma unroll
            for (int it = 0; it < 4; ++it) {
                int p = wave * 256 + it * 64 + lane;
                int r = p >> 3, q = (p & 7) ^ (r & 7);
                GLDS16(Wb + (long long)(n0 + r) * ldw + kk + q * 8, Bsu + p * 8);
            }
        }
        __syncthreads();

#pragma unroll
        for (int ku = 0; ku < KU; ++ku) {
            bf16* Asu = As + ku * 4096;
            bf16* Bsu = Bs + ku * 8192;
#pragma unroll
            for (int s = 0; s < 4; ++s) {
                int c = s * 2 + khalf;
                int q = (c ^ (l31 & 7)) * 8;
                bf16_8 a0 = *reinterpret_cast<const bf16_8*>(&Asu[l31 * 64 + q]);
                bf16_8 a1 = *reinterpret_cast<const bf16_8*>(&Asu[(32 + l31) * 64 + q]);
                bf16_8 b  = *reinterpret_cast<const bf16_8*>(&Bsu[(WN + l31) * 64 + q]);
                acc[0] = __builtin_amdgcn_mfma_f32_32x32x16_bf16(a0, b, acc[0], 0, 0, 0);
                acc[1] = __builtin_amdgcn_mfma_f32_32x32x16_bf16(a1, b, acc[1], 0, 0, 0);
            }
        }
        __syncthreads();
    }
}

// -------- merged projections: V full + Q/K head-1 (32x32 MFMA, BK=128) --------
__global__ __launch_bounds__(256) void proj_merged(
    const bf16* __restrict__ x_bf,
    const bf16* __restrict__ wv_bf, const float* __restrict__ bv, bf16* __restrict__ v_bf,
    const bf16* __restrict__ wq_bf, const float* __restrict__ bq, bf16* __restrict__ qh1,
    const bf16* __restrict__ wk_bf, const float* __restrict__ bk, bf16* __restrict__ kh1)
{
    __shared__ alignas(16) bf16 As[64 * 64 * 2];
    __shared__ alignas(16) bf16 Bs[128 * 64 * 2];
    const int tid = threadIdx.x;
    const int lane = tid & 63, wave = tid >> 6, l31 = lane & 31, khalf = lane >> 5;
    const int n0 = blockIdx.x * 128;

    int m0;
    const bf16* Ab; const bf16* Wb; const float* bvec; bf16* op;
    long long obase;
    int y = blockIdx.y;
    if (y < 64) { m0 = y * 64; Ab = x_bf; Wb = wv_bf; bvec = bv; op = v_bf; obase = 0; }
    else {
        int sub = y - 64;
        int batch = (sub >> 1) & 1;
        int sel = sub >> 2;
        m0 = (sub & 1) * 64;
        Ab = x_bf + (long long)batch * 2097152LL + 131072LL;   // rows 128..255 of batch slab
        Wb = sel ? wk_bf : wq_bf;
        bvec = sel ? bk : bq;
        op = sel ? kh1 : qh1;
        obase = (long long)batch * 131072LL;
    }

    f32_16 acc[2];
    gemm_core32<2>(Ab, 1024, Wb, 1024, 1024, m0, n0, tid, As, Bs, acc);

    const int WN = wave * 32;
    const int n = n0 + WN + l31;
    const float bn = bvec[n];
#pragma unroll
    for (int t = 0; t < 2; t++)
#pragma unroll
        for (int i = 0; i < 16; i++) {
            int m = m0 + t * 32 + (i & 3) + 8 * (i >> 2) + 4 * khalf;
            op[obase + (long long)m * 1024 + n] = (bf16)(acc[t][i] + bn);
        }
}

// -------- scores head-1 + exp + row partials, THEN inline V transpose (16x16, K=64) ---
__global__ __launch_bounds__(256) void scores_tr(
    const bf16* __restrict__ qh1, const bf16* __restrict__ kh1,
    const float* __restrict__ slopes,
    bf16* __restrict__ pb, float* __restrict__ spart,
    const unsigned short* __restrict__ v_bf, unsigned short* __restrict__ vt)
{
    __shared__ alignas(16) char smem[32768];
    bf16* As = (bf16*)smem;
    bf16* Bs = (bf16*)(smem + 16384);
    const int tid = threadIdx.x;
    const int lane = tid & 63, wave = tid >> 6, l15 = lane & 15, quad = lane >> 4;
    const int n0 = blockIdx.x * 128;
    const int m0 = blockIdx.y * 128;
    const int z  = blockIdx.z;

    f32_4 acc[4][4];
    gemm_core<128, 1>(qh1 + (long long)z * 131072LL, 64,
                      kh1 + (long long)z * 131072LL, 64, 64, m0, n0, tid, As, Bs, acc);

    const int WM = (wave >> 1) * 64;
    const int WN = (wave & 1) * 64;
    const float slope = slopes[1];
    long long obase = (long long)z * 4194304LL;
#pragma unroll
    for (int i = 0; i < 4; i++) {
#pragma unroll
        for (int rg = 0; rg < 4; rg++) {
            int m = m0 + WM + i * 16 + quad * 4 + rg;
            float rowpart = 0.0f;
#pragma unroll
            for (int j = 0; j < 4; j++) {
                int n = n0 + WN + j * 16 + l15;
                float v = acc[i][j][rg] * 0.125f - slope * fabsf((float)(m - n));
                float e = __expf(v);
                rowpart += e;
                pb[obase + (long long)m * 2048 + n] = (bf16)e;
            }
            rowpart += __shfl_xor(rowpart, 1, 64);
            rowpart += __shfl_xor(rowpart, 2, 64);
            rowpart += __shfl_xor(rowpart, 4, 64);
            rowpart += __shfl_xor(rowpart, 8, 64);
            if (l15 == 0)
                spart[((long long)z * 2048 + m) * 32 + (n0 >> 6) + (WN >> 6)] = rowpart;
        }
    }

    // ---- inline V transpose (flat-reshape mapping), 2 of 1024 tiles per block ----
    unsigned short* tile = (unsigned short*)smem;    // As region free after gemm_core
    int flat = z * 256 + blockIdx.y * 16 + blockIdx.x;   // 0..511
#pragma unroll
    for (int uu = 0; uu < 2; ++uu) {
        int u = flat * 2 + uu;                           // 0..1023
        int k0 = (u & 31) * 64, h = (u >> 5) & 15, b = u >> 9;
        const unsigned short* src = v_bf + (long long)b * 2097152LL + (long long)h * 131072LL;
#pragma unroll
        for (int p = 0; p < 8; p++) {
            int idx = tid + p * 256;
            int k = idx >> 5, dc = idx & 31;
            ushort2 w = *reinterpret_cast<const ushort2*>(&src[(long long)(k0 + k) * 64 + dc * 2]);
            tile[(dc * 2) * 66 + k]     = w.x;
            tile[(dc * 2 + 1) * 66 + k] = w.y;
        }
        __syncthreads();
        unsigned short* dst = vt + (long long)b * 2097152LL + (long long)h * 64 * 2048LL + k0;
#pragma unroll
        for (int p = 0; p < 8; p++) {
            int idx = tid + p * 256;
            int d = idx >> 5, kc = idx & 31;
            ushort2 w;
            w.x = tile[d * 66 + kc * 2];
            w.y = tile[d * 66 + kc * 2 + 1];
            *reinterpret_cast<ushort2*>(&dst[(long long)d * 2048 + kc * 2]) = w;
        }
        __syncthreads();
    }
}

// -------- PV fused (32x32 MFMA, BK=128): rsinv + probs_f in-loop + attn scatter ---
__global__ __launch_bounds__(256) void pv_fused(
    const bf16* __restrict__ pb, const bf16* __restrict__ vt,
    const float* __restrict__ spart,
    bf16* __restrict__ attn, float* __restrict__ probs_f)
{
    __shared__ alignas(16) bf16 As[64 * 64 * 2];
    __shared__ alignas(16) bf16 Bs[128 * 64 * 2];
    __shared__ float rs[64];
    const int tid = threadIdx.x;
    const int lane = tid & 63, wave = tid >> 6, l31 = lane & 31, khalf = lane >> 5;
    const int nx = blockIdx.x;          // n-tile AND probs k-slice index (both 8-wide)
    const int n0 = nx * 128;
    const int m0 = blockIdx.y * 64;
    const int z  = blockIdx.z;

    // prologue: rs[r] = 1 / sum_j spart[z*2048+m0+r][j]
    {
        int r = tid >> 2, part = tid & 3;
        const float* sp = spart + ((long long)z * 2048 + m0 + r) * 32 + part * 8;
        float4 a = *reinterpret_cast<const float4*>(sp);
        float4 b = *reinterpret_cast<const float4*>(sp + 4);
        float v = a.x + a.y + a.z + a.w + b.x + b.y + b.z + b.w;
        v += __shfl_xor(v, 1, 64);
        v += __shfl_xor(v, 2, 64);
        if (part == 0) rs[r] = 1.0f / v;
    }
    __syncthreads();

    const bf16* Ab = pb + (long long)z * 4194304LL;
    const bf16* Wb = vt + (long long)z * 2097152LL;
    const int WN = wave * 32;

    f32_16 acc[2];
    acc[0] = (f32_16)(0.0f);
    acc[1] = (f32_16)(0.0f);

    for (int k0 = 0; k0 < 2048; k0 += 128) {
#pragma unroll
        for (int ku = 0; ku < 2; ++ku) {
            bf16* Asu = As + ku * 4096;
            bf16* Bsu = Bs + ku * 8192;
            int kk = k0 + ku * 64;
#pragma unroll
            for (int it = 0; it < 2; ++it) {
                int p = wave * 128 + it * 64 + lane;
                int r = p >> 3, q = (p & 7) ^ (r & 7);
                GLDS16(Ab + (long long)(m0 + r) * 2048 + kk + q * 8, Asu + p * 8);
            }
#pragma unroll
            for (int it = 0; it < 4; ++it) {
                int p = wave * 256 + it * 64 + lane;
                int r = p >> 3, q = (p & 7) ^ (r & 7);
                GLDS16(Wb + (long long)(n0 + r) * 2048 + kk + q * 8, Bsu + p * 8);
            }
        }
        __syncthreads();

        // write probs_f (f32, normalized) for sub-tiles in this block's 256-col k-slice
#pragma unroll
        for (int ku = 0; ku < 2; ++ku) {
            int kk = k0 + ku * 64;
            if ((kk >> 8) == nx) {
                bf16* Asu = As + ku * 4096;
#pragma unroll
                for (int s0 = 0; s0 < 2; ++s0) {
                    int s = tid + s0 * 256;          // 0..511
                    int r = s >> 3, q = s & 7;
                    bf16_8 e = *reinterpret_cast<const bf16_8*>(&Asu[r * 64 + (q ^ (r & 7)) * 8]);
                    float inv = rs[r];
                    float4 o0, o1;
                    o0.x = (float)e[0] * inv; o0.y = (float)e[1] * inv;
                    o0.z = (float)e[2] * inv; o0.w = (float)e[3] * inv;
                    o1.x = (float)e[4] * inv; o1.y = (float)e[5] * inv;
                    o1.z = (float)e[6] * inv; o1.w = (float)e[7] * inv;
                    long long base = ((long long)z * 2048 + m0 + r) * 2048 + kk + q * 8;
                    *reinterpret_cast<float4*>(&probs_f[base])     = o0;
                    *reinterpret_cast<float4*>(&probs_f[base + 4]) = o1;
                }
            }
        }

#pragma unroll
        for (int ku = 0; ku < 2; ++ku) {
            bf16* Asu = As + ku * 4096;
            bf16* Bsu = Bs + ku * 8192;
#pragma unroll
            for (int s = 0; s < 4; ++s) {
                int c = s * 2 + khalf;
                int q = (c ^ (l31 & 7)) * 8;
                bf16_8 a0 = *reinterpret_cast<const bf16_8*>(&Asu[l31 * 64 + q]);
                bf16_8 a1 = *reinterpret_cast<const bf16_8*>(&Asu[(32 + l31) * 64 + q]);
                bf16_8 b  = *reinterpret_cast<const bf16_8*>(&Bsu[(WN + l31) * 64 + q]);
                acc[0] = __builtin_amdgcn_mfma_f32_32x32x16_bf16(a0, b, acc[0], 0, 0, 0);
                acc[1] = __builtin_amdgcn_mfma_f32_32x32x16_bf16(a1, b, acc[1], 0, 0, 0);
            }
        }
        __syncthreads();
    }

    // epilogue: scale by rs[row], scatter to flat attn layout
    long long obase = (long long)z * 2097152LL;
    const int n = n0 + WN + l31;
#pragma unroll
    for (int t = 0; t < 2; t++)
#pragma unroll
        for (int i = 0; i < 16; i++) {
            int ml = t * 32 + (i & 3) + 8 * (i >> 2) + 4 * khalf;
            int m = m0 + ml;
            float v = acc[t][i] * rs[ml];
            long long off = obase + ((long long)(n >> 6)) * 131072LL + (long long)m * 64 + (n & 63);
            attn[off] = (bf16)v;
        }
}

// -------- out projection (32x32 MFMA, BK=128): f32 out + bias --------
__global__ __launch_bounds__(256) void out_proj(
    const bf16* __restrict__ attn, const bf16* __restrict__ wo_bf,
    const float* __restrict__ bo, float* __restrict__ out_f)
{
    __shared__ alignas(16) bf16 As[64 * 64 * 2];
    __shared__ alignas(16) bf16 Bs[128 * 64 * 2];
    const int tid = threadIdx.x;
    const int lane = tid & 63, wave = tid >> 6, l31 = lane & 31, khalf = lane >> 5;
    const int n0 = blockIdx.x * 128;
    const int m0 = blockIdx.y * 64;

    f32_16 acc[2];
    gemm_core32<2>(attn, 1024, wo_bf, 1024, 1024, m0, n0, tid, As, Bs, acc);

    const int WN = wave * 32;
    const int n = n0 + WN + l31;
    const float bn = bo[n];
#pragma unroll
    for (int t = 0; t < 2; t++)
#pragma unroll
        for (int i = 0; i < 16; i++) {
            int m = m0 + t * 32 + (i & 3) + 8 * (i >> 2) + 4 * khalf;
            out_f[(long long)m * 1024 + n] = acc[t][i] + bn;
        }
}

// ---------------- launcher: 5 launches ----------------
extern "C" void kernel_launch(void* const* d_in, const int* in_sizes, int n_in,
                              void* d_out, int out_size, void* d_ws, size_t ws_size,
                              hipStream_t stream) {
    const float* x      = (const float*)d_in[0];
    const float* Wq     = (const float*)d_in[1];
    const float* bq     = (const float*)d_in[2];
    const float* Wk     = (const float*)d_in[3];
    const float* bk     = (const float*)d_in[4];
    const float* Wv     = (const float*)d_in[5];
    const float* bv     = (const float*)d_in[6];
    const float* Wo     = (const float*)d_in[7];
    const float* bo     = (const float*)d_in[8];
    const float* slopes = (const float*)d_in[9];

    // B=2, S=2048, E=1024, H=16, hd=64
    char* w = (char*)d_ws;
    bf16* x_bf  = (bf16*)w;  w += 4096LL * 1024 * 2;
    bf16* wq_bf = (bf16*)w;  w += 1024LL * 1024 * 2;
    bf16* wk_bf = (bf16*)w;  w += 1024LL * 1024 * 2;
    bf16* wv_bf = (bf16*)w;  w += 1024LL * 1024 * 2;
    bf16* wo_bf = (bf16*)w;  w += 1024LL * 1024 * 2;
    bf16* qh1   = (bf16*)w;  w += 2LL * 131072 * 2;
    bf16* kh1   = (bf16*)w;  w += 2LL * 131072 * 2;
    bf16* v_bf  = (bf16*)w;  w += 4096LL * 1024 * 2;
    bf16* vt    = (bf16*)w;  w += 2LL * 1024 * 2048 * 2;
    bf16* attn  = (bf16*)w;  w += 4096LL * 1024 * 2;
    bf16* pb    = (bf16*)w;  w += 2LL * 2048 * 2048 * 2;
    float* spart = (float*)w; w += 4096LL * 32 * 4;

    float* out_f   = (float*)d_out;                // (B,S,E)
    float* probs_f = (float*)d_out + 4194304LL;    // (B,1,S,S)

    // 1) converts
    convert_all<<<2048, 256, 0, stream>>>(x, Wq, Wk, Wv, Wo, x_bf, wq_bf, wk_bf, wv_bf, wo_bf);

    // 2) merged projections: V full + Q/K head-1
    proj_merged<<<dim3(8, 72, 1), 256, 0, stream>>>(
        x_bf, wv_bf, bv, v_bf, wq_bf, bq, qh1, wk_bf, bk, kh1);

    // 3) scores + exp + spart, then inline V transpose
    scores_tr<<<dim3(16, 16, 2), 256, 0, stream>>>(
        qh1, kh1, slopes, pb, spart,
        (const unsigned short*)v_bf, (unsigned short*)vt);

    // 4) PV fused: rsinv from spart, probs_f (d_out), attn scatter
    pv_fused<<<dim3(8, 32, 2), 256, 0, stream>>>(pb, vt, spart, attn, probs_f);

    // 5) out projection -> d_out
    out_proj<<<dim3(8, 64, 1), 256, 0, stream>>>(attn, wo_bf, bo, out_f);
}